// Round 9
// baseline (22145.753 us; speedup 1.0000x reference)
//
#include <hip/hip_runtime.h>
#include <stdint.h>

typedef unsigned long long u64;
typedef _Float16 h4 __attribute__((ext_vector_type(4)));

#define Bq 64
#define Tq 256
#define Hq 512
#define Eq 512
#define Vq 32000

__device__ __forceinline__ float sigmoid_f(float x) { return 1.0f / (1.0f + expf(-x)); }

__device__ __forceinline__ unsigned f2sortable(float f) {
    unsigned u = __float_as_uint(f);
    return (u & 0x80000000u) ? ~u : (u | 0x80000000u);
}

// async global->LDS, 16B per lane; LDS dest is wave-uniform base + lane*16
__device__ __forceinline__ void gl_lds16(const float* g, float* l) {
    __builtin_amdgcn_global_load_lds(
        (const __attribute__((address_space(1))) void*)g,
        (__attribute__((address_space(3))) void*)l, 16, 0, 0);
}

// non-temporal variant (aux bit1 = nt/slc): streaming reads that should not
// evict L2-resident LSTM weights / hT. Read-only data -> any cache-policy
// bits are correctness-safe.
__device__ __forceinline__ void gl_lds16_nt(const void* g, float* l) {
    __builtin_amdgcn_global_load_lds(
        (const __attribute__((address_space(1))) void*)g,
        (__attribute__((address_space(3))) void*)l, 16, 0, 2);
}

// State layout "stateT": element (k, b) stored at (k>>2)*256 + b*4 + (k&3).

#define DOT4(acc, a, wv) \
    acc = fmaf((a).w, (wv).w, fmaf((a).z, (wv).z, fmaf((a).y, (wv).y, fmaf((a).x, (wv).x, (acc)))))

// fp16-W mixed dot: W rounded to fp16 (rel err 2^-12), h exact fp32.
#define DOT4H(acc, a, wv) \
    acc = fmaf((a).w, (float)(wv).w, fmaf((a).z, (float)(wv).z, \
          fmaf((a).y, (float)(wv).y, fmaf((a).x, (float)(wv).x, (acc)))))

// ---------------------------------------------------------------------------
// One-time (per launch) Wfc fp32 -> fp16 conversion. 8000 blocks x 256 thr,
// 8 elems/thread = exactly 32000*512.
// ---------------------------------------------------------------------------
__global__ __launch_bounds__(256) void wfc_to_f16(
    const float4* __restrict__ w4, uint4* __restrict__ o4)
{
    size_t i = (size_t)blockIdx.x * 256 + threadIdx.x;
    float4 a = w4[2 * i], b = w4[2 * i + 1];
    union { _Float16 h[8]; uint4 u; } p;
    p.h[0] = (_Float16)a.x; p.h[1] = (_Float16)a.y;
    p.h[2] = (_Float16)a.z; p.h[3] = (_Float16)a.w;
    p.h[4] = (_Float16)b.x; p.h[5] = (_Float16)b.y;
    p.h[6] = (_Float16)b.z; p.h[7] = (_Float16)b.w;
    o4[i] = p.u;
}

// ---------------------------------------------------------------------------
// LSTM layer kernel (unchanged, proven).
// ---------------------------------------------------------------------------
__global__ __launch_bounds__(256) void lstm_layer_kernel(
    const float* __restrict__ emb,
    const int*   __restrict__ xcol,
    const u64*   __restrict__ amax_in,
    const float* __restrict__ inpT,
    const float* __restrict__ hprevT,
    float*       __restrict__ houtT,
    float*       __restrict__ cstate,
    const float* __restrict__ Wih,
    const float* __restrict__ Whh,
    const float* __restrict__ bih,
    const float* __restrict__ bhh,
    u64*         __restrict__ amax_reset,
    int t, int is_layer0)
{
    __shared__ float4 wlds[1024];             // 16KB
    const int h    = blockIdx.x;
    const int tid  = threadIdx.x;
    const int wave = __builtin_amdgcn_readfirstlane(tid >> 6);
    const int lane = tid & 63;

    if (amax_reset && blockIdx.x == 0 && wave == 3) amax_reset[lane] = 0;

    const float4* Wih4 = (const float4*)Wih;
    const float4* Whh4 = (const float4*)Whh;
    #pragma unroll
    for (int i = 0; i < 4; ++i) {
        int g   = i * 256 + tid;
        int s   = g >> 7;
        int off = g & 127;
        const float4* src = (s < 4) ? Wih4 : Whh4;
        wlds[g] = src[(size_t)((s & 3) * Hq + h) * 128 + off];
    }
    __syncthreads();

    const int part = wave >> 1;
    const int kq0  = (wave & 1) << 6;

    float acc0 = 0.f, acc1 = 0.f, acc2 = 0.f, acc3 = 0.f;

    if (part == 0 && is_layer0) {
        int row = (t == 0) ? xcol[lane * Tq] : (int)(~(unsigned)amax_in[lane]);
        const float4* a4 = (const float4*)(emb + (size_t)row * Eq);
        #pragma unroll 4
        for (int i = 0; i < 64; ++i) {
            float4 a = a4[kq0 + i];
            int kq = kq0 + i;
            float4 w0 = wlds[0 * 128 + kq];
            float4 w1 = wlds[1 * 128 + kq];
            float4 w2 = wlds[2 * 128 + kq];
            float4 w3 = wlds[3 * 128 + kq];
            DOT4(acc0, a, w0); DOT4(acc1, a, w1);
            DOT4(acc2, a, w2); DOT4(acc3, a, w3);
        }
    } else {
        const float4* a4 = (const float4*)(part ? hprevT : inpT);
        #pragma unroll 4
        for (int i = 0; i < 64; ++i) {
            int kq = kq0 + i;
            float4 a = a4[kq * 64 + lane];
            float4 w0 = wlds[(part * 4 + 0) * 128 + kq];
            float4 w1 = wlds[(part * 4 + 1) * 128 + kq];
            float4 w2 = wlds[(part * 4 + 2) * 128 + kq];
            float4 w3 = wlds[(part * 4 + 3) * 128 + kq];
            DOT4(acc0, a, w0); DOT4(acc1, a, w1);
            DOT4(acc2, a, w2); DOT4(acc3, a, w3);
        }
    }

    __shared__ float red[4][4][64];
    red[wave][0][lane] = acc0;
    red[wave][1][lane] = acc1;
    red[wave][2][lane] = acc2;
    red[wave][3][lane] = acc3;
    __syncthreads();

    if (wave == 0) {
        float gi = red[0][0][lane] + red[1][0][lane] + red[2][0][lane] + red[3][0][lane]
                 + bih[0 * Hq + h] + bhh[0 * Hq + h];
        float gf = red[0][1][lane] + red[1][1][lane] + red[2][1][lane] + red[3][1][lane]
                 + bih[1 * Hq + h] + bhh[1 * Hq + h];
        float gg = red[0][2][lane] + red[1][2][lane] + red[2][2][lane] + red[3][2][lane]
                 + bih[2 * Hq + h] + bhh[2 * Hq + h];
        float go = red[0][3][lane] + red[1][3][lane] + red[2][3][lane] + red[3][3][lane]
                 + bih[3 * Hq + h] + bhh[3 * Hq + h];
        float cold = cstate[h * 64 + lane];
        float cn = sigmoid_f(gf) * cold + sigmoid_f(gi) * tanhf(gg);
        float hn = sigmoid_f(go) * tanhf(cn);
        cstate[h * 64 + lane] = cn;
        houtT[(h >> 2) * 256 + lane * 4 + (h & 3)] = hn;
    }
}

// ---------------------------------------------------------------------------
// FC head, fp16-W variant. W chunk = 64 rows x 64 k x 2B = 8KB (16B chunks
// swizzled: LDS slot s of row r holds global 16B-chunk s ^ (r>>3), so the
// 8-rgrp broadcast read of k-slot sl spreads over 8 distinct 16B slots =
// 128B = all banks). A (hT) staging/reads unchanged (fp32, proven swizzle).
// Buffers: 2 x (8KB W + 16KB A) = 48KB LDS.
// ---------------------------------------------------------------------------
__global__ __launch_bounds__(256) void fc_kernel_f16(
    const float*    __restrict__ hT,
    const _Float16* __restrict__ Wh,    // (V, 512) fp16
    const float*    __restrict__ bfc,
    float*          __restrict__ out,
    u64*            __restrict__ amax,
    int write_out)
{
    __shared__ float lds[2][6144];      // [buf][ W 2048 w | A 4096 w ]
    const int tid  = threadIdx.x;
    const int wave = __builtin_amdgcn_readfirstlane(tid >> 6);
    const int lane = tid & 63;
    const int rgrp = lane >> 3;
    const int bgrp = lane & 7;
    const int v0   = blockIdx.x * 64;

    float acc[8][8];
    #pragma unroll
    for (int j = 0; j < 8; ++j)
        #pragma unroll
        for (int i = 0; i < 8; ++i) acc[j][i] = 0.f;

#define STAGE16(cc, dst)                                                      \
    {                                                                         \
        _Pragma("unroll")                                                     \
        for (int it = 0; it < 2; ++it) {          /* W: 8KB, nt */            \
            int g = it * 256 + tid;                                           \
            int r = g >> 3, s = g & 7;                                        \
            gl_lds16_nt(Wh + (size_t)(v0 + r) * 512 + (cc) * 64              \
                           + (((s ^ (r >> 3)) & 7) << 3),                     \
                        (dst) + it * 1024 + wave * 256);                      \
        }                                                                     \
        _Pragma("unroll")                                                     \
        for (int it = 0; it < 4; ++it) {          /* A: 16KB, cached */       \
            int g = it * 256 + tid;                                           \
            int kqr = g >> 6, u = g & 63;                                     \
            int b = (u & 56) | ((u & 7) ^ (u >> 3));                          \
            gl_lds16(hT + (size_t)((cc) * 16 + kqr) * 256 + b * 4,            \
                     (dst) + 2048 + it * 1024 + wave * 256);                  \
        }                                                                     \
    }

    float* cur = lds[0];
    float* nxt = lds[1];

    STAGE16(0, cur)
    __syncthreads();

    for (int c = 0; c < 8; ++c) {
        if (c < 7) STAGE16(c + 1, nxt)

        #pragma unroll
        for (int kq = 0; kq < 4; ++kq) {
            const int sl = wave * 4 + kq;       // k-slot 0..15
            const _Float16* wbase = (const _Float16*)cur;
            h4 wv[8];
            float4 av[8];
            #pragma unroll
            for (int j = 0; j < 8; ++j)
                wv[j] = *(const h4*)(wbase + (rgrp * 8 + j) * 64
                                     + ((((sl >> 1) ^ rgrp) & 7) << 3)
                                     + ((sl & 1) << 2));
            #pragma unroll
            for (int i = 0; i < 8; ++i)
                av[i] = *(const float4*)(cur + 2048 + sl * 256 + ((bgrp * 8 + (i ^ bgrp)) << 2));
            #pragma unroll
            for (int j = 0; j < 8; ++j)
                #pragma unroll
                for (int i = 0; i < 8; ++i)
                    DOT4H(acc[j][i], av[i], wv[j]);
        }

        __syncthreads();
        float* tmp = cur; cur = nxt; nxt = tmp;
    }

    // ---- cross-wave K reduction into accbuf = lds[0] (64x64 fp32) ----
    float* accbuf = lds[0];
    for (int w = 0; w < 4; ++w) {
        if (wave == w) {
            #pragma unroll
            for (int j = 0; j < 8; ++j) {
                float* p = accbuf + (rgrp * 8 + j) * 64 + bgrp * 8;
                if (w == 0) {
                    *(float4*)p       = make_float4(acc[j][0], acc[j][1], acc[j][2], acc[j][3]);
                    *(float4*)(p + 4) = make_float4(acc[j][4], acc[j][5], acc[j][6], acc[j][7]);
                } else {
                    float4 a0 = *(const float4*)p;
                    float4 a1 = *(const float4*)(p + 4);
                    a0.x += acc[j][0]; a0.y += acc[j][1]; a0.z += acc[j][2]; a0.w += acc[j][3];
                    a1.x += acc[j][4]; a1.y += acc[j][5]; a1.z += acc[j][6]; a1.w += acc[j][7];
                    *(float4*)p       = a0;
                    *(float4*)(p + 4) = a1;
                }
            }
        }
        __syncthreads();
    }

    const int b  = tid & 63;
    const int rq = wave;
    float best = -__builtin_huge_valf();
    int bi = 0;
    float lg[16];
    #pragma unroll
    for (int n = 0; n < 16; ++n) {
        int r = rq * 16 + n;
        float v = accbuf[r * 64 + b] + bfc[v0 + r];
        lg[n] = v;
        if (v > best) { best = v; bi = v0 + r; }
    }
    u64 pack = ((u64)f2sortable(best) << 32) | (u64)(~(unsigned)bi);

    u64* redm = (u64*)lds[1];
    redm[rq * 64 + b] = pack;
    __syncthreads();
    if (rq == 0) {
        u64 m  = redm[b];
        u64 m1 = redm[64 + b];  if (m1 > m) m = m1;
        u64 m2 = redm[128 + b]; if (m2 > m) m = m2;
        u64 m3 = redm[192 + b]; if (m3 > m) m = m3;
        atomicMax(&amax[b], m);
    }

    if (write_out) {
        #pragma unroll
        for (int n = 0; n < 16; ++n)
            out[(size_t)b * Vq + v0 + rq * 16 + n] = lg[n];
    }
}

// ---------------------------------------------------------------------------
// FC head, fp32 (round-0 proven) — fallback when ws_size can't hold Wfc16.
// ---------------------------------------------------------------------------
__global__ __launch_bounds__(256) void fc_kernel(
    const float* __restrict__ hT,
    const float* __restrict__ Wfc,
    const float* __restrict__ bfc,
    float*       __restrict__ out,
    u64*         __restrict__ amax,
    int write_out)
{
    __shared__ float lds[2][8192];
    const int tid  = threadIdx.x;
    const int wave = __builtin_amdgcn_readfirstlane(tid >> 6);
    const int lane = tid & 63;
    const int rgrp = lane >> 3;
    const int bgrp = lane & 7;
    const int v0   = blockIdx.x * 64;

    float acc[8][8];
    #pragma unroll
    for (int j = 0; j < 8; ++j)
        #pragma unroll
        for (int i = 0; i < 8; ++i) acc[j][i] = 0.f;

#define STAGE_CHUNK(cc, dst)                                                  \
    {                                                                         \
        const int k0_ = (cc) * 64;                                            \
        _Pragma("unroll")                                                     \
        for (int it = 0; it < 4; ++it) {                                      \
            int g = it * 256 + tid;                                           \
            int r = g >> 4, sp = g & 15;                                      \
            int gk = k0_ + (((sp ^ (r >> 3)) & 15) << 2);                     \
            gl_lds16(Wfc + (size_t)(v0 + r) * 512 + gk,                       \
                     (dst) + it * 1024 + wave * 256);                         \
        }                                                                     \
        _Pragma("unroll")                                                     \
        for (int it = 0; it < 4; ++it) {                                      \
            int g = it * 256 + tid;                                           \
            int kqr = g >> 6, u = g & 63;                                     \
            int b = (u & 56) | ((u & 7) ^ (u >> 3));                          \
            gl_lds16(hT + (size_t)((cc) * 16 + kqr) * 256 + b * 4,            \
                     (dst) + 4096 + it * 1024 + wave * 256);                  \
        }                                                                     \
    }

    float* cur = lds[0];
    float* nxt = lds[1];

    STAGE_CHUNK(0, cur)
    __syncthreads();

    for (int c = 0; c < 8; ++c) {
        if (c < 7) STAGE_CHUNK(c + 1, nxt)

        #pragma unroll
        for (int kq = 0; kq < 4; ++kq) {
            const int sl = wave * 4 + kq;
            float4 wv[8], av[8];
            #pragma unroll
            for (int j = 0; j < 8; ++j)
                wv[j] = *(const float4*)(cur + (rgrp * 8 + j) * 64 + (((sl ^ rgrp) & 15) << 2));
            #pragma unroll
            for (int i = 0; i < 8; ++i)
                av[i] = *(const float4*)(cur + 4096 + sl * 256 + ((bgrp * 8 + (i ^ bgrp)) << 2));
            #pragma unroll
            for (int j = 0; j < 8; ++j)
                #pragma unroll
                for (int i = 0; i < 8; ++i)
                    DOT4(acc[j][i], av[i], wv[j]);
        }

        __syncthreads();
        float* tmp = cur; cur = nxt; nxt = tmp;
    }

    float* accbuf = lds[0];
    for (int w = 0; w < 4; ++w) {
        if (wave == w) {
            #pragma unroll
            for (int j = 0; j < 8; ++j) {
                float* p = accbuf + (rgrp * 8 + j) * 64 + bgrp * 8;
                if (w == 0) {
                    *(float4*)p       = make_float4(acc[j][0], acc[j][1], acc[j][2], acc[j][3]);
                    *(float4*)(p + 4) = make_float4(acc[j][4], acc[j][5], acc[j][6], acc[j][7]);
                } else {
                    float4 a0 = *(const float4*)p;
                    float4 a1 = *(const float4*)(p + 4);
                    a0.x += acc[j][0]; a0.y += acc[j][1]; a0.z += acc[j][2]; a0.w += acc[j][3];
                    a1.x += acc[j][4]; a1.y += acc[j][5]; a1.z += acc[j][6]; a1.w += acc[j][7];
                    *(float4*)p       = a0;
                    *(float4*)(p + 4) = a1;
                }
            }
        }
        __syncthreads();
    }

    const int b  = tid & 63;
    const int rq = wave;
    float best = -__builtin_huge_valf();
    int bi = 0;
    float lg[16];
    #pragma unroll
    for (int n = 0; n < 16; ++n) {
        int r = rq * 16 + n;
        float v = accbuf[r * 64 + b] + bfc[v0 + r];
        lg[n] = v;
        if (v > best) { best = v; bi = v0 + r; }
    }
    u64 pack = ((u64)f2sortable(best) << 32) | (u64)(~(unsigned)bi);

    u64* redm = (u64*)lds[1];
    redm[rq * 64 + b] = pack;
    __syncthreads();
    if (rq == 0) {
        u64 m  = redm[b];
        u64 m1 = redm[64 + b];  if (m1 > m) m = m1;
        u64 m2 = redm[128 + b]; if (m2 > m) m = m2;
        u64 m3 = redm[192 + b]; if (m3 > m) m = m3;
        atomicMax(&amax[b], m);
    }

    if (write_out) {
        #pragma unroll
        for (int n = 0; n < 16; ++n)
            out[(size_t)b * Vq + v0 + rq * 16 + n] = lg[n];
    }
}

extern "C" void kernel_launch(void* const* d_in, const int* in_sizes, int n_in,
                              void* d_out, int out_size, void* d_ws, size_t ws_size,
                              hipStream_t stream)
{
    const int*   x   = (const int*)d_in[0];
    const float* emb = (const float*)d_in[1];
    const float* Wih = (const float*)d_in[2];
    const float* Whh = (const float*)d_in[3];
    const float* bih = (const float*)d_in[4];
    const float* bhh = (const float*)d_in[5];
    const float* Wfc = (const float*)d_in[6];
    const float* bfc = (const float*)d_in[7];
    float* out = (float*)d_out;

    float* ws = (float*)d_ws;
    float* h0T[2] = { ws,          ws + 32768 };
    float* h1T[2] = { ws + 65536,  ws + 98304 };
    float* c0 = ws + 131072;
    float* c1 = ws + 163840;
    u64* amax = (u64*)(ws + 196608);

    // fp16 Wfc cache at the 1MB mark of the workspace (guarded by ws_size;
    // rounds 3/4 died on OOB workspace access — never exceed ws_size).
    const size_t W16_OFF   = 262144;                       // floats
    const size_t need_ws   = W16_OFF * 4 + (size_t)Vq * 512 * 2;
    const int    use_f16   = (ws_size >= need_ws);
    _Float16*    w16       = (_Float16*)(ws + W16_OFF);

    hipMemsetAsync(d_ws, 0, 196608 * sizeof(float) + 64 * sizeof(u64), stream);

    if (use_f16)
        wfc_to_f16<<<8000, 256, 0, stream>>>((const float4*)Wfc, (uint4*)w16);

    const size_t WL = (size_t)4 * Hq * 512;
    for (int t = 0; t < Tq; ++t) {
        int rd = t & 1, wr = (t + 1) & 1;
        lstm_layer_kernel<<<512, 256, 0, stream>>>(
            emb, x, amax, nullptr, h0T[rd], h0T[wr], c0,
            Wih, Whh, bih, bhh,
            nullptr, t, 1);
        lstm_layer_kernel<<<512, 256, 0, stream>>>(
            emb, x, amax, h0T[wr], h1T[rd], h1T[wr], c1,
            Wih + WL, Whh + WL, bih + 4 * Hq, bhh + 4 * Hq,
            amax, t, 0);
        if (use_f16)
            fc_kernel_f16<<<500, 256, 0, stream>>>(
                h1T[wr], w16, bfc, out, amax, (t == Tq - 1) ? 1 : 0);
        else
            fc_kernel<<<500, 256, 0, stream>>>(
                h1T[wr], Wfc, bfc, out, amax, (t == Tq - 1) ? 1 : 0);
    }
}